// Round 10
// baseline (1084.960 us; speedup 1.0000x reference)
//
#include <hip/hip_runtime.h>

// ---------------------------------------------------------------------------
// ResidualGCN: 3x (GCNConv -> BN -> ReLU (+res)) -> Linear head
// N=100000, E=1.6M, dims 128/128/64, fp32.
//
// R4: edge_hist atomic-bound -> R5 packed u64 atomic + rank-based fill (validated:
//     1094 -> 988us, hist/fill left top-5).
// R8 counters: 3x gcn_gather ~124.5us each now dominate. FETCH 405MB =
//     8 XCDs x 51MB h (per-XCD L2 re-fetch of random rows) at 3.7TB/s fabric.
// R9 (this): remove the ~150us of BN dispatches around the fixed gather cost:
//   - bn_stats fused into gather epilogue (grid-stride + block reduce + atomics)
//   - bn_apply/relu/residual fused into next gemm's A-staging; gemm3 side-stores
//     h2 IN-PLACE over C1 (same thread reads then writes its own row -> safe).
// ---------------------------------------------------------------------------

typedef unsigned long long u64;
#define DEG_MASK 0xFFFFFFFFFFFFULL
#define WSCALE 2147483648.0f  // 2^31

// One wave: edge_index int64 (flag=1) vs int32 (flag=0) device-side probe.
__global__ void detect_i64(const int* __restrict__ ei32, int* __restrict__ flag) {
  int lane = threadIdx.x & 63;
  int v = ei32[2 * lane + 1];
  unsigned long long b = __ballot(v == 0);
  if (lane == 0) *flag = (b == ~0ull) ? 1 : 0;
}

__global__ __launch_bounds__(256) void init_k(u64* __restrict__ packed,
                                              float* __restrict__ stats, int n) {
  int i = blockIdx.x * 256 + threadIdx.x;
  if (i < n) packed[i] = 0ull;       // [cnt:16 | sum(w)*2^31:48]
  if (i < 768) stats[i] = 0.0f;      // 3 layers x (sum[128], sumsq[128])
}

// histogram by target column: ONE packed 64-bit atomic per edge.
__global__ __launch_bounds__(256) void edge_hist(const int* __restrict__ ei32,
                                                 const float* __restrict__ w,
                                                 u64* __restrict__ packed,
                                                 unsigned short* __restrict__ rank,
                                                 const int* __restrict__ flag, int e) {
  int i = blockIdx.x * 256 + threadIdx.x;
  if (i >= e) return;
  int is64 = *flag;
  int c = is64 ? ei32[2 * (e + i)] : ei32[e + i];
  u64 add = ((u64)1 << 48) | (u64)(unsigned)__float2uint_rn(w[i] * WSCALE);
  u64 old = atomicAdd(&packed[c], add);
  rank[i] = (unsigned short)(old >> 48);
}

__global__ __launch_bounds__(256) void scan_blocksum(const u64* __restrict__ packed,
                                                     int* __restrict__ bsum, int n) {
  __shared__ int s[256];
  int i = blockIdx.x * 256 + threadIdx.x;
  s[threadIdx.x] = (i < n) ? (int)(packed[i] >> 48) : 0;
  __syncthreads();
  for (int off = 128; off > 0; off >>= 1) {
    if (threadIdx.x < off) s[threadIdx.x] += s[threadIdx.x + off];
    __syncthreads();
  }
  if (threadIdx.x == 0) bsum[blockIdx.x] = s[0];
}

__global__ __launch_bounds__(256) void scan_small(int* __restrict__ bsum, int nb) {
  __shared__ int s[256];
  __shared__ int carry_s;
  if (threadIdx.x == 0) carry_s = 0;
  __syncthreads();
  for (int base = 0; base < nb; base += 256) {
    int idx = base + threadIdx.x;
    int v = (idx < nb) ? bsum[idx] : 0;
    s[threadIdx.x] = v;
    __syncthreads();
    for (int off = 1; off < 256; off <<= 1) {
      int t = (threadIdx.x >= (unsigned)off) ? s[threadIdx.x - off] : 0;
      __syncthreads();
      s[threadIdx.x] += t;
      __syncthreads();
    }
    int carry = carry_s;
    if (idx < nb) bsum[idx] = carry + s[threadIdx.x] - v;  // exclusive
    __syncthreads();
    if (threadIdx.x == 255) carry_s = carry + s[255];
    __syncthreads();
  }
}

__global__ __launch_bounds__(256) void scan_final(const u64* __restrict__ packed,
                                                  const int* __restrict__ boff,
                                                  int* __restrict__ rowptr,
                                                  float* __restrict__ dinv,
                                                  int n, int e_total) {
  __shared__ int s[256];
  int i = blockIdx.x * 256 + threadIdx.x;
  u64 p = (i < n) ? packed[i] : 0ull;
  int v = (int)(p >> 48);
  s[threadIdx.x] = v;
  __syncthreads();
  for (int off = 1; off < 256; off <<= 1) {
    int t = (threadIdx.x >= (unsigned)off) ? s[threadIdx.x - off] : 0;
    __syncthreads();
    s[threadIdx.x] += t;
    __syncthreads();
  }
  if (i < n) {
    rowptr[i] = boff[blockIdx.x] + s[threadIdx.x] - v;
    float deg = 1.0f + (float)(p & DEG_MASK) * (1.0f / WSCALE);
    dinv[i] = rsqrtf(deg);
  }
  if (i == 0) rowptr[n] = e_total;
}

// NO atomics: slot = rowptr[col] + rank.
__global__ __launch_bounds__(256) void edge_fill(const int* __restrict__ ei32,
                                                 const float* __restrict__ w,
                                                 const float* __restrict__ dinv,
                                                 const int* __restrict__ rowptr,
                                                 const unsigned short* __restrict__ rank,
                                                 int2* __restrict__ csr,
                                                 const int* __restrict__ flag, int e) {
  int i = blockIdx.x * 256 + threadIdx.x;
  if (i >= e) return;
  int is64 = *flag;
  int r, c;
  if (is64) { r = ei32[2 * i]; c = ei32[2 * (e + i)]; }
  else      { r = ei32[i];     c = ei32[e + i]; }
  float nrm = dinv[r] * w[i] * dinv[c];
  int pos = rowptr[c] + (int)rank[i];
  csr[pos] = make_int2(r, __float_as_int(nrm));
}

// out[N,OC] = f(A...)[N,128] @ W[128,OC] (+ bias). OC = 32*CPT.
// MODE 0: A = A0                       (layer-1 gemm, raw x)
// MODE 1: A = relu(bn0(A0))            (gemm2: A0=C1)
// MODE 2: A = relu(bn1(A1)+relu(bn0(A0))), side-store A into side[] (gemm3;
//         side==A0 -> in-place h2 over C1; per-thread read-then-write, safe)
// MODE 3: A = relu(bn1(A1)+A0)         (head: A0=h2, A1=C3)
template <int CPT, int MODE>
__global__ __launch_bounds__(256) void gemm_k128f(const float* A0, const float* A1,
                                                  const float* __restrict__ scsh0,
                                                  const float* __restrict__ scsh1,
                                                  float* side,
                                                  const float* __restrict__ W,
                                                  const float* __restrict__ bias,
                                                  float* __restrict__ out, int n) {
  constexpr int OC = 32 * CPT;
  __shared__ float As[64][128];
  const int tid = threadIdx.x;
  const int r0 = blockIdx.x * 64;
  const int c4s = (tid & 31) << 2;   // feature quad, constant per thread
  float4 sc0, sh0, sc1, sh1;
  if (MODE == 1 || MODE == 2) {
    sc0 = *reinterpret_cast<const float4*>(&scsh0[c4s]);
    sh0 = *reinterpret_cast<const float4*>(&scsh0[128 + c4s]);
  }
  if (MODE == 2 || MODE == 3) {
    sc1 = *reinterpret_cast<const float4*>(&scsh1[c4s]);
    sh1 = *reinterpret_cast<const float4*>(&scsh1[128 + c4s]);
  }
  #pragma unroll
  for (int i = 0; i < 8; ++i) {
    int idx = tid + i * 256;
    int row = idx >> 5;
    int gr = r0 + row;
    float4 v = make_float4(0.f, 0.f, 0.f, 0.f);
    if (gr < n) {
      size_t base = (size_t)gr * 128 + c4s;
      if (MODE == 0) {
        v = *reinterpret_cast<const float4*>(&A0[base]);
      } else if (MODE == 1) {
        float4 a = *reinterpret_cast<const float4*>(&A0[base]);
        v.x = fmaxf(fmaf(a.x, sc0.x, sh0.x), 0.f);
        v.y = fmaxf(fmaf(a.y, sc0.y, sh0.y), 0.f);
        v.z = fmaxf(fmaf(a.z, sc0.z, sh0.z), 0.f);
        v.w = fmaxf(fmaf(a.w, sc0.w, sh0.w), 0.f);
      } else if (MODE == 2) {
        float4 a = *reinterpret_cast<const float4*>(&A0[base]);
        float4 b = *reinterpret_cast<const float4*>(&A1[base]);
        float hx = fmaxf(fmaf(a.x, sc0.x, sh0.x), 0.f);
        float hy = fmaxf(fmaf(a.y, sc0.y, sh0.y), 0.f);
        float hz = fmaxf(fmaf(a.z, sc0.z, sh0.z), 0.f);
        float hw = fmaxf(fmaf(a.w, sc0.w, sh0.w), 0.f);
        v.x = fmaxf(fmaf(b.x, sc1.x, sh1.x) + hx, 0.f);
        v.y = fmaxf(fmaf(b.y, sc1.y, sh1.y) + hy, 0.f);
        v.z = fmaxf(fmaf(b.z, sc1.z, sh1.z) + hz, 0.f);
        v.w = fmaxf(fmaf(b.w, sc1.w, sh1.w) + hw, 0.f);
        *reinterpret_cast<float4*>(&side[base]) = v;   // h2 in-place
      } else {  // MODE 3
        float4 a = *reinterpret_cast<const float4*>(&A0[base]);
        float4 b = *reinterpret_cast<const float4*>(&A1[base]);
        v.x = fmaxf(fmaf(b.x, sc1.x, sh1.x) + a.x, 0.f);
        v.y = fmaxf(fmaf(b.y, sc1.y, sh1.y) + a.y, 0.f);
        v.z = fmaxf(fmaf(b.z, sc1.z, sh1.z) + a.z, 0.f);
        v.w = fmaxf(fmaf(b.w, sc1.w, sh1.w) + a.w, 0.f);
      }
    }
    *reinterpret_cast<float4*>(&As[row][c4s]) = v;
  }
  __syncthreads();

  const int lc = (tid & 31) * CPT;
  const int lr = (tid >> 5) * 8;
  float acc[8][CPT];
  #pragma unroll
  for (int i = 0; i < 8; ++i)
    #pragma unroll
    for (int j = 0; j < CPT; ++j) acc[i][j] = 0.f;

  #pragma unroll 2
  for (int k4 = 0; k4 < 128; k4 += 4) {
    float a[8][4];
    #pragma unroll
    for (int i = 0; i < 8; ++i) {
      float4 t = *reinterpret_cast<const float4*>(&As[lr + i][k4]);
      a[i][0] = t.x; a[i][1] = t.y; a[i][2] = t.z; a[i][3] = t.w;
    }
    #pragma unroll
    for (int kk = 0; kk < 4; ++kk) {
      float wv[CPT];
      const float* wrow = &W[(size_t)(k4 + kk) * OC + lc];
      if constexpr (CPT == 4) {
        float4 t = *reinterpret_cast<const float4*>(wrow);
        wv[0] = t.x; wv[1] = t.y; wv[2] = t.z; wv[3] = t.w;
      } else {
        float2 t = *reinterpret_cast<const float2*>(wrow);
        wv[0] = t.x; wv[1] = t.y;
      }
      #pragma unroll
      for (int i = 0; i < 8; ++i)
        #pragma unroll
        for (int j = 0; j < CPT; ++j)
          acc[i][j] = fmaf(a[i][kk], wv[j], acc[i][j]);
    }
  }

  float bv[CPT];
  #pragma unroll
  for (int j = 0; j < CPT; ++j) bv[j] = bias ? bias[lc + j] : 0.f;
  #pragma unroll
  for (int i = 0; i < 8; ++i) {
    int gr = r0 + lr + i;
    if (gr < n) {
      if constexpr (CPT == 4) {
        float4 o = make_float4(acc[i][0] + bv[0], acc[i][1] + bv[1],
                               acc[i][2] + bv[2], acc[i][3] + bv[3]);
        *reinterpret_cast<float4*>(&out[(size_t)gr * OC + lc]) = o;
      } else {
        float2 o = make_float2(acc[i][0] + bv[0], acc[i][1] + bv[1]);
        *reinterpret_cast<float2*>(&out[(size_t)gr * OC + lc]) = o;
      }
    }
  }
}

// wave-per-node CSR gather + fused BN statistics.
// grid-stride (2048 blocks = 32 waves/CU); per-thread s/q accum for its two
// features, 4-wave LDS reduce, 256 atomics per block.
__global__ __launch_bounds__(256) void gcn_gather(const float* __restrict__ h,
                                                  const int* __restrict__ rowptr,
                                                  const int2* __restrict__ csr,
                                                  const float* __restrict__ dinv,
                                                  const float* __restrict__ bias,
                                                  float* __restrict__ out,
                                                  float* __restrict__ stats, int n) {
  const int wave = threadIdx.x >> 6;
  const int lane = threadIdx.x & 63;
  const float2* hp = reinterpret_cast<const float2*>(h);
  const int f = lane * 2;
  const float bx = bias[f], by = bias[f + 1];
  float s0 = 0.f, q0 = 0.f, s1 = 0.f, q1 = 0.f;

  for (int node = blockIdx.x * 4 + wave; node < n; node += gridDim.x * 4) {
    float di = dinv[node];
    float2 hv = hp[(size_t)node * 64 + lane];
    float sw = di * di;
    float ax = sw * hv.x, ay = sw * hv.y;
    int e0 = rowptr[node], e1 = rowptr[node + 1];
    int e = e0;
    for (; e + 3 < e1; e += 4) {   // 4 independent 512B row loads in flight
      int2 pa = csr[e];
      int2 pb = csr[e + 1];
      int2 pc = csr[e + 2];
      int2 pd = csr[e + 3];
      float2 sa = hp[(size_t)pa.x * 64 + lane];
      float2 sb = hp[(size_t)pb.x * 64 + lane];
      float2 sc = hp[(size_t)pc.x * 64 + lane];
      float2 sd = hp[(size_t)pd.x * 64 + lane];
      float na = __int_as_float(pa.y), nb = __int_as_float(pb.y);
      float nc = __int_as_float(pc.y), nd = __int_as_float(pd.y);
      ax = fmaf(na, sa.x, ax); ay = fmaf(na, sa.y, ay);
      ax = fmaf(nb, sb.x, ax); ay = fmaf(nb, sb.y, ay);
      ax = fmaf(nc, sc.x, ax); ay = fmaf(nc, sc.y, ay);
      ax = fmaf(nd, sd.x, ax); ay = fmaf(nd, sd.y, ay);
    }
    for (; e < e1; ++e) {
      int2 p = csr[e];
      float2 sv = hp[(size_t)p.x * 64 + lane];
      float nm = __int_as_float(p.y);
      ax = fmaf(nm, sv.x, ax); ay = fmaf(nm, sv.y, ay);
    }
    float ox = ax + bx, oy = ay + by;
    reinterpret_cast<float2*>(out)[(size_t)node * 64 + lane] = make_float2(ox, oy);
    s0 += ox; q0 = fmaf(ox, ox, q0);
    s1 += oy; q1 = fmaf(oy, oy, q1);
  }

  __shared__ float red[4][256];
  red[wave][lane * 4 + 0] = s0;
  red[wave][lane * 4 + 1] = q0;
  red[wave][lane * 4 + 2] = s1;
  red[wave][lane * 4 + 3] = q1;
  __syncthreads();
  if (wave == 0) {
    #pragma unroll
    for (int w = 1; w < 4; ++w) {
      s0 += red[w][lane * 4 + 0];
      q0 += red[w][lane * 4 + 1];
      s1 += red[w][lane * 4 + 2];
      q1 += red[w][lane * 4 + 3];
    }
    atomicAdd(&stats[f], s0);
    atomicAdd(&stats[128 + f], q0);
    atomicAdd(&stats[f + 1], s1);
    atomicAdd(&stats[128 + f + 1], q1);
  }
}

__global__ void bn_finalize(const float* __restrict__ stats,
                            const float* __restrict__ g,
                            const float* __restrict__ be,
                            float* __restrict__ scsh, float inv_n) {
  int f = threadIdx.x;  // 128 threads
  float mean = stats[f] * inv_n;
  float var = stats[128 + f] * inv_n - mean * mean;
  float sc = g[f] * rsqrtf(var + 1e-5f);
  scsh[f] = sc;
  scsh[128 + f] = be[f] - mean * sc;
}

extern "C" void kernel_launch(void* const* d_in, const int* in_sizes, int n_in,
                              void* d_out, int out_size, void* d_ws, size_t ws_size,
                              hipStream_t stream) {
  const float* x   = (const float*)d_in[0];
  const int*   ei  = (const int*)d_in[1];      // int32 on device (probed for int64)
  const float* ew  = (const float*)d_in[2];
  const float* W1  = (const float*)d_in[3];
  const float* b1  = (const float*)d_in[4];
  const float* g1  = (const float*)d_in[5];
  const float* be1 = (const float*)d_in[6];
  const float* W2  = (const float*)d_in[7];
  const float* b2  = (const float*)d_in[8];
  const float* g2  = (const float*)d_in[9];
  const float* be2 = (const float*)d_in[10];
  const float* W3  = (const float*)d_in[11];
  const float* b3  = (const float*)d_in[12];
  const float* g3  = (const float*)d_in[13];
  const float* be3 = (const float*)d_in[14];
  const float* Wh  = (const float*)d_in[15];
  const float* bh  = (const float*)d_in[16];

  const int N = in_sizes[0] / 128;
  const int E = in_sizes[2];

  char* base = (char*)d_ws;
  size_t off = 0;
  auto alloc = [&](size_t bytes) -> void* {
    off = (off + 511) & ~size_t(511);
    void* p = base + off;
    off += bytes;
    return p;
  };
  int*            flag    = (int*)alloc(4);
  u64*            packed  = (u64*)alloc((size_t)N * 8);
  float*          dinv    = (float*)alloc((size_t)N * 4);
  int*            rowptr  = (int*)alloc((size_t)(N + 1) * 4);
  int*            bsum    = (int*)alloc(1024 * 4);
  float*          stats   = (float*)alloc(768 * 4);
  float*          scshAll = (float*)alloc(768 * 4);
  unsigned short* rank    = (unsigned short*)alloc((size_t)E * 2);
  int2*           csr     = (int2*)alloc((size_t)E * 8);
  float*          P       = (float*)alloc((size_t)N * 128 * 4);  // gemm out
  float*          Q       = (float*)alloc((size_t)N * 128 * 4);  // C1 -> h2
  float*          R       = (float*)alloc((size_t)N * 128 * 4);  // C2 -> C3
  (void)ws_size; (void)n_in; (void)out_size;

  const int nb = (N + 255) / 256;
  const int eb = (E + 255) / 256;
  const int gb = (N + 63) / 64;
  const int cb = 2048;  // grid-stride gather: 8 blocks/CU = 32 waves/CU

  // ---- graph normalization + CSR build ----
  detect_i64<<<1, 64, 0, stream>>>(ei, flag);
  init_k<<<nb, 256, 0, stream>>>(packed, stats, N);
  edge_hist<<<eb, 256, 0, stream>>>(ei, ew, packed, rank, flag, E);
  scan_blocksum<<<nb, 256, 0, stream>>>(packed, bsum, N);
  scan_small<<<1, 256, 0, stream>>>(bsum, nb);
  scan_final<<<nb, 256, 0, stream>>>(packed, bsum, rowptr, dinv, N, E);
  edge_fill<<<eb, 256, 0, stream>>>(ei, ew, dinv, rowptr, rank, csr, flag, E);

  // ---- layer 1: P = x@W1; Q = C1 = agg(P) [+stats0]
  gemm_k128f<4, 0><<<gb, 256, 0, stream>>>(x, nullptr, nullptr, nullptr, nullptr,
                                           W1, nullptr, P, N);
  gcn_gather<<<cb, 256, 0, stream>>>(P, rowptr, csr, dinv, b1, Q, stats + 0, N);
  bn_finalize<<<1, 128, 0, stream>>>(stats + 0, g1, be1, scshAll + 0, 1.0f / N);

  // ---- layer 2: P = relu(bn1(C1))@W2; R = C2 = agg(P) [+stats1]
  gemm_k128f<4, 1><<<gb, 256, 0, stream>>>(Q, nullptr, scshAll + 0, nullptr, nullptr,
                                           W2, nullptr, P, N);
  gcn_gather<<<cb, 256, 0, stream>>>(P, rowptr, csr, dinv, b2, R, stats + 256, N);
  bn_finalize<<<1, 128, 0, stream>>>(stats + 256, g2, be2, scshAll + 256, 1.0f / N);

  // ---- layer 3: h2 = relu(bn2(C2)+relu(bn1(C1))) (side-stored over Q);
  //               P = h2@W3; R = C3 = agg(P) [+stats2]  (C2 dead after gemm)
  gemm_k128f<4, 2><<<gb, 256, 0, stream>>>(Q, R, scshAll + 0, scshAll + 256, Q,
                                           W3, nullptr, P, N);
  gcn_gather<<<cb, 256, 0, stream>>>(P, rowptr, csr, dinv, b3, R, stats + 512, N);
  bn_finalize<<<1, 128, 0, stream>>>(stats + 512, g3, be3, scshAll + 512, 1.0f / N);

  // ---- head: d_out = relu(bn3(C3)+h2) @ Wh + bh
  gemm_k128f<2, 3><<<gb, 256, 0, stream>>>(Q, R, nullptr, scshAll + 512, nullptr,
                                           Wh, bh, (float*)d_out, N);
}

// Round 12
// 946.165 us; speedup vs baseline: 1.1467x; 1.1467x over previous
//
#include <hip/hip_runtime.h>

// ---------------------------------------------------------------------------
// ResidualGCN: 3x (GCNConv -> BN -> ReLU (+res)) -> Linear head
// N=100000, E=1.6M, dims 128/128/64, fp32.
//
// R4: edge_hist atomic-bound -> R5 packed u64 atomic + rank-free fill
//     (validated 1094 -> 988us).
// R10 post-mortem: grid-stride persistent gather (2048 blocks) TANKED gather
//     BW 3.74 -> 2.32 TB/s (124.5 -> 205us each): inter-node serialization per
//     wave + exact-fill tail imbalance. REVERTED to one-node-per-wave.
//     GEMM-side bn_apply/relu/residual fusion KEPT (validated correct, absmax
//     0.0156; removes 3 bn_apply streaming dispatches).
// ---------------------------------------------------------------------------

typedef unsigned long long u64;
#define DEG_MASK 0xFFFFFFFFFFFFULL
#define WSCALE 2147483648.0f  // 2^31

// One wave: edge_index int64 (flag=1) vs int32 (flag=0) device-side probe.
__global__ void detect_i64(const int* __restrict__ ei32, int* __restrict__ flag) {
  int lane = threadIdx.x & 63;
  int v = ei32[2 * lane + 1];
  unsigned long long b = __ballot(v == 0);
  if (lane == 0) *flag = (b == ~0ull) ? 1 : 0;
}

__global__ __launch_bounds__(256) void init_k(u64* __restrict__ packed,
                                              float* __restrict__ stats, int n) {
  int i = blockIdx.x * 256 + threadIdx.x;
  if (i < n) packed[i] = 0ull;       // [cnt:16 | sum(w)*2^31:48]
  if (i < 768) stats[i] = 0.0f;      // 3 layers x (sum[128], sumsq[128])
}

// histogram by target column: ONE packed 64-bit atomic per edge.
__global__ __launch_bounds__(256) void edge_hist(const int* __restrict__ ei32,
                                                 const float* __restrict__ w,
                                                 u64* __restrict__ packed,
                                                 unsigned short* __restrict__ rank,
                                                 const int* __restrict__ flag, int e) {
  int i = blockIdx.x * 256 + threadIdx.x;
  if (i >= e) return;
  int is64 = *flag;
  int c = is64 ? ei32[2 * (e + i)] : ei32[e + i];
  u64 add = ((u64)1 << 48) | (u64)(unsigned)__float2uint_rn(w[i] * WSCALE);
  u64 old = atomicAdd(&packed[c], add);
  rank[i] = (unsigned short)(old >> 48);
}

__global__ __launch_bounds__(256) void scan_blocksum(const u64* __restrict__ packed,
                                                     int* __restrict__ bsum, int n) {
  __shared__ int s[256];
  int i = blockIdx.x * 256 + threadIdx.x;
  s[threadIdx.x] = (i < n) ? (int)(packed[i] >> 48) : 0;
  __syncthreads();
  for (int off = 128; off > 0; off >>= 1) {
    if (threadIdx.x < off) s[threadIdx.x] += s[threadIdx.x + off];
    __syncthreads();
  }
  if (threadIdx.x == 0) bsum[blockIdx.x] = s[0];
}

__global__ __launch_bounds__(256) void scan_small(int* __restrict__ bsum, int nb) {
  __shared__ int s[256];
  __shared__ int carry_s;
  if (threadIdx.x == 0) carry_s = 0;
  __syncthreads();
  for (int base = 0; base < nb; base += 256) {
    int idx = base + threadIdx.x;
    int v = (idx < nb) ? bsum[idx] : 0;
    s[threadIdx.x] = v;
    __syncthreads();
    for (int off = 1; off < 256; off <<= 1) {
      int t = (threadIdx.x >= (unsigned)off) ? s[threadIdx.x - off] : 0;
      __syncthreads();
      s[threadIdx.x] += t;
      __syncthreads();
    }
    int carry = carry_s;
    if (idx < nb) bsum[idx] = carry + s[threadIdx.x] - v;  // exclusive
    __syncthreads();
    if (threadIdx.x == 255) carry_s = carry + s[255];
    __syncthreads();
  }
}

__global__ __launch_bounds__(256) void scan_final(const u64* __restrict__ packed,
                                                  const int* __restrict__ boff,
                                                  int* __restrict__ rowptr,
                                                  float* __restrict__ dinv,
                                                  int n, int e_total) {
  __shared__ int s[256];
  int i = blockIdx.x * 256 + threadIdx.x;
  u64 p = (i < n) ? packed[i] : 0ull;
  int v = (int)(p >> 48);
  s[threadIdx.x] = v;
  __syncthreads();
  for (int off = 1; off < 256; off <<= 1) {
    int t = (threadIdx.x >= (unsigned)off) ? s[threadIdx.x - off] : 0;
    __syncthreads();
    s[threadIdx.x] += t;
    __syncthreads();
  }
  if (i < n) {
    rowptr[i] = boff[blockIdx.x] + s[threadIdx.x] - v;
    float deg = 1.0f + (float)(p & DEG_MASK) * (1.0f / WSCALE);
    dinv[i] = rsqrtf(deg);
  }
  if (i == 0) rowptr[n] = e_total;
}

// NO atomics: slot = rowptr[col] + rank.
__global__ __launch_bounds__(256) void edge_fill(const int* __restrict__ ei32,
                                                 const float* __restrict__ w,
                                                 const float* __restrict__ dinv,
                                                 const int* __restrict__ rowptr,
                                                 const unsigned short* __restrict__ rank,
                                                 int2* __restrict__ csr,
                                                 const int* __restrict__ flag, int e) {
  int i = blockIdx.x * 256 + threadIdx.x;
  if (i >= e) return;
  int is64 = *flag;
  int r, c;
  if (is64) { r = ei32[2 * i]; c = ei32[2 * (e + i)]; }
  else      { r = ei32[i];     c = ei32[e + i]; }
  float nrm = dinv[r] * w[i] * dinv[c];
  int pos = rowptr[c] + (int)rank[i];
  csr[pos] = make_int2(r, __float_as_int(nrm));
}

// out[N,OC] = f(A...)[N,128] @ W[128,OC] (+ bias). OC = 32*CPT.
// MODE 0: A = A0                       (layer-1 gemm, raw x)
// MODE 1: A = relu(bn0(A0))            (gemm2: A0=C1)
// MODE 2: A = relu(bn1(A1)+relu(bn0(A0))), side-store A into side[] (gemm3;
//         side==A0 -> in-place h2 over C1; per-thread read-then-write, safe)
// MODE 3: A = relu(bn1(A1)+A0)         (head: A0=h2, A1=C3)
template <int CPT, int MODE>
__global__ __launch_bounds__(256) void gemm_k128f(const float* A0, const float* A1,
                                                  const float* __restrict__ scsh0,
                                                  const float* __restrict__ scsh1,
                                                  float* side,
                                                  const float* __restrict__ W,
                                                  const float* __restrict__ bias,
                                                  float* __restrict__ out, int n) {
  constexpr int OC = 32 * CPT;
  __shared__ float As[64][128];
  const int tid = threadIdx.x;
  const int r0 = blockIdx.x * 64;
  const int c4s = (tid & 31) << 2;   // feature quad, constant per thread
  float4 sc0, sh0, sc1, sh1;
  if (MODE == 1 || MODE == 2) {
    sc0 = *reinterpret_cast<const float4*>(&scsh0[c4s]);
    sh0 = *reinterpret_cast<const float4*>(&scsh0[128 + c4s]);
  }
  if (MODE == 2 || MODE == 3) {
    sc1 = *reinterpret_cast<const float4*>(&scsh1[c4s]);
    sh1 = *reinterpret_cast<const float4*>(&scsh1[128 + c4s]);
  }
  #pragma unroll
  for (int i = 0; i < 8; ++i) {
    int idx = tid + i * 256;
    int row = idx >> 5;
    int gr = r0 + row;
    float4 v = make_float4(0.f, 0.f, 0.f, 0.f);
    if (gr < n) {
      size_t base = (size_t)gr * 128 + c4s;
      if (MODE == 0) {
        v = *reinterpret_cast<const float4*>(&A0[base]);
      } else if (MODE == 1) {
        float4 a = *reinterpret_cast<const float4*>(&A0[base]);
        v.x = fmaxf(fmaf(a.x, sc0.x, sh0.x), 0.f);
        v.y = fmaxf(fmaf(a.y, sc0.y, sh0.y), 0.f);
        v.z = fmaxf(fmaf(a.z, sc0.z, sh0.z), 0.f);
        v.w = fmaxf(fmaf(a.w, sc0.w, sh0.w), 0.f);
      } else if (MODE == 2) {
        float4 a = *reinterpret_cast<const float4*>(&A0[base]);
        float4 b = *reinterpret_cast<const float4*>(&A1[base]);
        float hx = fmaxf(fmaf(a.x, sc0.x, sh0.x), 0.f);
        float hy = fmaxf(fmaf(a.y, sc0.y, sh0.y), 0.f);
        float hz = fmaxf(fmaf(a.z, sc0.z, sh0.z), 0.f);
        float hw = fmaxf(fmaf(a.w, sc0.w, sh0.w), 0.f);
        v.x = fmaxf(fmaf(b.x, sc1.x, sh1.x) + hx, 0.f);
        v.y = fmaxf(fmaf(b.y, sc1.y, sh1.y) + hy, 0.f);
        v.z = fmaxf(fmaf(b.z, sc1.z, sh1.z) + hz, 0.f);
        v.w = fmaxf(fmaf(b.w, sc1.w, sh1.w) + hw, 0.f);
        *reinterpret_cast<float4*>(&side[base]) = v;   // h2 in-place
      } else {  // MODE 3
        float4 a = *reinterpret_cast<const float4*>(&A0[base]);
        float4 b = *reinterpret_cast<const float4*>(&A1[base]);
        v.x = fmaxf(fmaf(b.x, sc1.x, sh1.x) + a.x, 0.f);
        v.y = fmaxf(fmaf(b.y, sc1.y, sh1.y) + a.y, 0.f);
        v.z = fmaxf(fmaf(b.z, sc1.z, sh1.z) + a.z, 0.f);
        v.w = fmaxf(fmaf(b.w, sc1.w, sh1.w) + a.w, 0.f);
      }
    }
    *reinterpret_cast<float4*>(&As[row][c4s]) = v;
  }
  __syncthreads();

  const int lc = (tid & 31) * CPT;
  const int lr = (tid >> 5) * 8;
  float acc[8][CPT];
  #pragma unroll
  for (int i = 0; i < 8; ++i)
    #pragma unroll
    for (int j = 0; j < CPT; ++j) acc[i][j] = 0.f;

  #pragma unroll 2
  for (int k4 = 0; k4 < 128; k4 += 4) {
    float a[8][4];
    #pragma unroll
    for (int i = 0; i < 8; ++i) {
      float4 t = *reinterpret_cast<const float4*>(&As[lr + i][k4]);
      a[i][0] = t.x; a[i][1] = t.y; a[i][2] = t.z; a[i][3] = t.w;
    }
    #pragma unroll
    for (int kk = 0; kk < 4; ++kk) {
      float wv[CPT];
      const float* wrow = &W[(size_t)(k4 + kk) * OC + lc];
      if constexpr (CPT == 4) {
        float4 t = *reinterpret_cast<const float4*>(wrow);
        wv[0] = t.x; wv[1] = t.y; wv[2] = t.z; wv[3] = t.w;
      } else {
        float2 t = *reinterpret_cast<const float2*>(wrow);
        wv[0] = t.x; wv[1] = t.y;
      }
      #pragma unroll
      for (int i = 0; i < 8; ++i)
        #pragma unroll
        for (int j = 0; j < CPT; ++j)
          acc[i][j] = fmaf(a[i][kk], wv[j], acc[i][j]);
    }
  }

  float bv[CPT];
  #pragma unroll
  for (int j = 0; j < CPT; ++j) bv[j] = bias ? bias[lc + j] : 0.f;
  #pragma unroll
  for (int i = 0; i < 8; ++i) {
    int gr = r0 + lr + i;
    if (gr < n) {
      if constexpr (CPT == 4) {
        float4 o = make_float4(acc[i][0] + bv[0], acc[i][1] + bv[1],
                               acc[i][2] + bv[2], acc[i][3] + bv[3]);
        *reinterpret_cast<float4*>(&out[(size_t)gr * OC + lc]) = o;
      } else {
        float2 o = make_float2(acc[i][0] + bv[0], acc[i][1] + bv[1]);
        *reinterpret_cast<float2*>(&out[(size_t)gr * OC + lc]) = o;
      }
    }
  }
}

// wave-per-node CSR gather (R8-validated form: one node per wave, hardware
// block scheduling, 4 independent 512B row loads in flight).
__global__ __launch_bounds__(256) void gcn_gather(const float* __restrict__ h,
                                                  const int* __restrict__ rowptr,
                                                  const int2* __restrict__ csr,
                                                  const float* __restrict__ dinv,
                                                  const float* __restrict__ bias,
                                                  float* __restrict__ out, int n) {
  int wave = threadIdx.x >> 6;
  int lane = threadIdx.x & 63;
  int node = blockIdx.x * 4 + wave;
  if (node >= n) return;
  const float2* hp = reinterpret_cast<const float2*>(h);
  float di = dinv[node];
  float2 hv = hp[(size_t)node * 64 + lane];
  float s = di * di;
  float ax = s * hv.x, ay = s * hv.y;
  int e0 = rowptr[node], e1 = rowptr[node + 1];
  int e = e0;
  for (; e + 3 < e1; e += 4) {
    int2 pa = csr[e];
    int2 pb = csr[e + 1];
    int2 pc = csr[e + 2];
    int2 pd = csr[e + 3];
    float2 sa = hp[(size_t)pa.x * 64 + lane];
    float2 sb = hp[(size_t)pb.x * 64 + lane];
    float2 sc = hp[(size_t)pc.x * 64 + lane];
    float2 sd = hp[(size_t)pd.x * 64 + lane];
    float na = __int_as_float(pa.y), nb = __int_as_float(pb.y);
    float nc = __int_as_float(pc.y), nd = __int_as_float(pd.y);
    ax = fmaf(na, sa.x, ax); ay = fmaf(na, sa.y, ay);
    ax = fmaf(nb, sb.x, ax); ay = fmaf(nb, sb.y, ay);
    ax = fmaf(nc, sc.x, ax); ay = fmaf(nc, sc.y, ay);
    ax = fmaf(nd, sd.x, ax); ay = fmaf(nd, sd.y, ay);
  }
  for (; e < e1; ++e) {
    int2 p = csr[e];
    float2 sv = hp[(size_t)p.x * 64 + lane];
    float nm = __int_as_float(p.y);
    ax = fmaf(nm, sv.x, ax); ay = fmaf(nm, sv.y, ay);
  }
  int f = lane * 2;
  float2 o = make_float2(ax + bias[f], ay + bias[f + 1]);
  reinterpret_cast<float2*>(out)[(size_t)node * 64 + lane] = o;
}

__global__ __launch_bounds__(256) void bn_stats(const float* __restrict__ h,
                                                float* __restrict__ stats, int n) {
  int f = threadIdx.x & 127;
  int half = threadIdx.x >> 7;
  float s = 0.f, q = 0.f;
  for (int r = blockIdx.x * 2 + half; r < n; r += gridDim.x * 2) {
    float v = h[(size_t)r * 128 + f];
    s += v;
    q = fmaf(v, v, q);
  }
  __shared__ float ls[256], lq[256];
  ls[threadIdx.x] = s; lq[threadIdx.x] = q;
  __syncthreads();
  if (half == 0) {
    s += ls[threadIdx.x + 128];
    q += lq[threadIdx.x + 128];
    atomicAdd(&stats[f], s);
    atomicAdd(&stats[128 + f], q);
  }
}

__global__ void bn_finalize(const float* __restrict__ stats,
                            const float* __restrict__ g,
                            const float* __restrict__ be,
                            float* __restrict__ scsh, float inv_n) {
  int f = threadIdx.x;  // 128 threads
  float mean = stats[f] * inv_n;
  float var = stats[128 + f] * inv_n - mean * mean;
  float sc = g[f] * rsqrtf(var + 1e-5f);
  scsh[f] = sc;
  scsh[128 + f] = be[f] - mean * sc;
}

extern "C" void kernel_launch(void* const* d_in, const int* in_sizes, int n_in,
                              void* d_out, int out_size, void* d_ws, size_t ws_size,
                              hipStream_t stream) {
  const float* x   = (const float*)d_in[0];
  const int*   ei  = (const int*)d_in[1];      // int32 on device (probed for int64)
  const float* ew  = (const float*)d_in[2];
  const float* W1  = (const float*)d_in[3];
  const float* b1  = (const float*)d_in[4];
  const float* g1  = (const float*)d_in[5];
  const float* be1 = (const float*)d_in[6];
  const float* W2  = (const float*)d_in[7];
  const float* b2  = (const float*)d_in[8];
  const float* g2  = (const float*)d_in[9];
  const float* be2 = (const float*)d_in[10];
  const float* W3  = (const float*)d_in[11];
  const float* b3  = (const float*)d_in[12];
  const float* g3  = (const float*)d_in[13];
  const float* be3 = (const float*)d_in[14];
  const float* Wh  = (const float*)d_in[15];
  const float* bh  = (const float*)d_in[16];

  const int N = in_sizes[0] / 128;
  const int E = in_sizes[2];

  char* base = (char*)d_ws;
  size_t off = 0;
  auto alloc = [&](size_t bytes) -> void* {
    off = (off + 511) & ~size_t(511);
    void* p = base + off;
    off += bytes;
    return p;
  };
  int*            flag    = (int*)alloc(4);
  u64*            packed  = (u64*)alloc((size_t)N * 8);
  float*          dinv    = (float*)alloc((size_t)N * 4);
  int*            rowptr  = (int*)alloc((size_t)(N + 1) * 4);
  int*            bsum    = (int*)alloc(1024 * 4);
  float*          stats   = (float*)alloc(768 * 4);
  float*          scshAll = (float*)alloc(768 * 4);
  unsigned short* rank    = (unsigned short*)alloc((size_t)E * 2);
  int2*           csr     = (int2*)alloc((size_t)E * 8);
  float*          P       = (float*)alloc((size_t)N * 128 * 4);  // gemm out
  float*          Q       = (float*)alloc((size_t)N * 128 * 4);  // C1 -> h2
  float*          R       = (float*)alloc((size_t)N * 128 * 4);  // C2 -> C3
  (void)ws_size; (void)n_in; (void)out_size;

  const int nb = (N + 255) / 256;
  const int eb = (E + 255) / 256;
  const int gb = (N + 63) / 64;
  const int cb = (N + 3) / 4;   // one node per wave (R8-validated schedule)

  // ---- graph normalization + CSR build ----
  detect_i64<<<1, 64, 0, stream>>>(ei, flag);
  init_k<<<nb, 256, 0, stream>>>(packed, stats, N);
  edge_hist<<<eb, 256, 0, stream>>>(ei, ew, packed, rank, flag, E);
  scan_blocksum<<<nb, 256, 0, stream>>>(packed, bsum, N);
  scan_small<<<1, 256, 0, stream>>>(bsum, nb);
  scan_final<<<nb, 256, 0, stream>>>(packed, bsum, rowptr, dinv, N, E);
  edge_fill<<<eb, 256, 0, stream>>>(ei, ew, dinv, rowptr, rank, csr, flag, E);

  // ---- layer 1: P = x@W1; Q = C1 = agg(P); stats0
  gemm_k128f<4, 0><<<gb, 256, 0, stream>>>(x, nullptr, nullptr, nullptr, nullptr,
                                           W1, nullptr, P, N);
  gcn_gather<<<cb, 256, 0, stream>>>(P, rowptr, csr, dinv, b1, Q, N);
  bn_stats<<<512, 256, 0, stream>>>(Q, stats + 0, N);
  bn_finalize<<<1, 128, 0, stream>>>(stats + 0, g1, be1, scshAll + 0, 1.0f / N);

  // ---- layer 2: P = relu(bn1(C1))@W2; R = C2 = agg(P); stats1
  gemm_k128f<4, 1><<<gb, 256, 0, stream>>>(Q, nullptr, scshAll + 0, nullptr, nullptr,
                                           W2, nullptr, P, N);
  gcn_gather<<<cb, 256, 0, stream>>>(P, rowptr, csr, dinv, b2, R, N);
  bn_stats<<<512, 256, 0, stream>>>(R, stats + 256, N);
  bn_finalize<<<1, 128, 0, stream>>>(stats + 256, g2, be2, scshAll + 256, 1.0f / N);

  // ---- layer 3: h2 = relu(bn2(C2)+relu(bn1(C1))) (side-stored over Q);
  //               P = h2@W3; R = C3 = agg(P); stats2  (C2 dead after gemm)
  gemm_k128f<4, 2><<<gb, 256, 0, stream>>>(Q, R, scshAll + 0, scshAll + 256, Q,
                                           W3, nullptr, P, N);
  gcn_gather<<<cb, 256, 0, stream>>>(P, rowptr, csr, dinv, b3, R, N);
  bn_stats<<<512, 256, 0, stream>>>(R, stats + 512, N);
  bn_finalize<<<1, 128, 0, stream>>>(stats + 512, g3, be3, scshAll + 512, 1.0f / N);

  // ---- head: d_out = relu(bn3(C3)+h2) @ Wh + bh
  gemm_k128f<2, 3><<<gb, 256, 0, stream>>>(Q, R, nullptr, scshAll + 512, nullptr,
                                           Wh, bh, (float*)d_out, N);
}

// Round 13
// 816.855 us; speedup vs baseline: 1.3282x; 1.1583x over previous
//
#include <hip/hip_runtime.h>

// ---------------------------------------------------------------------------
// ResidualGCN: 3x (GCNConv -> BN -> ReLU (+res)) -> Linear head
// N=100000, E=1.6M, dims 128/128/64, fp32 (gather operand bf16).
//
// Validated history: R5 packed-u64 hist + rank fill (1094->988); R11 revert of
// persistent gather + GEMM-side BN fusion (988->946; gathers 122.5us @3.8TB/s,
// FETCH 405MB = 8 XCD x 51MB random row fills).
// R13 (this): gather operand in BF16. P's only consumer is the gather, so the
// conv GEMMs write ONLY a bf16 P (RNE pack in epilogue, 25.6MB vs 51.2MB) and
// the gather reads 256B rows -> halves the 405MB fabric traffic. All
// accumulation stays fp32. Predicted gather ~70us, total ~780us.
// ---------------------------------------------------------------------------

typedef unsigned long long u64;
#define DEG_MASK 0xFFFFFFFFFFFFULL
#define WSCALE 2147483648.0f  // 2^31

__device__ __forceinline__ unsigned bf16pack2(float a, float b) {
  unsigned ua = __float_as_uint(a); ua += 0x7FFF + ((ua >> 16) & 1);
  unsigned ub = __float_as_uint(b); ub += 0x7FFF + ((ub >> 16) & 1);
  return (ua >> 16) | (ub & 0xFFFF0000u);
}

// One wave: edge_index int64 (flag=1) vs int32 (flag=0) device-side probe.
__global__ void detect_i64(const int* __restrict__ ei32, int* __restrict__ flag) {
  int lane = threadIdx.x & 63;
  int v = ei32[2 * lane + 1];
  unsigned long long b = __ballot(v == 0);
  if (lane == 0) *flag = (b == ~0ull) ? 1 : 0;
}

__global__ __launch_bounds__(256) void init_k(u64* __restrict__ packed,
                                              float* __restrict__ stats, int n) {
  int i = blockIdx.x * 256 + threadIdx.x;
  if (i < n) packed[i] = 0ull;       // [cnt:16 | sum(w)*2^31:48]
  if (i < 768) stats[i] = 0.0f;      // 3 layers x (sum[128], sumsq[128])
}

// histogram by target column: ONE packed 64-bit atomic per edge.
__global__ __launch_bounds__(256) void edge_hist(const int* __restrict__ ei32,
                                                 const float* __restrict__ w,
                                                 u64* __restrict__ packed,
                                                 unsigned short* __restrict__ rank,
                                                 const int* __restrict__ flag, int e) {
  int i = blockIdx.x * 256 + threadIdx.x;
  if (i >= e) return;
  int is64 = *flag;
  int c = is64 ? ei32[2 * (e + i)] : ei32[e + i];
  u64 add = ((u64)1 << 48) | (u64)(unsigned)__float2uint_rn(w[i] * WSCALE);
  u64 old = atomicAdd(&packed[c], add);
  rank[i] = (unsigned short)(old >> 48);
}

__global__ __launch_bounds__(256) void scan_blocksum(const u64* __restrict__ packed,
                                                     int* __restrict__ bsum, int n) {
  __shared__ int s[256];
  int i = blockIdx.x * 256 + threadIdx.x;
  s[threadIdx.x] = (i < n) ? (int)(packed[i] >> 48) : 0;
  __syncthreads();
  for (int off = 128; off > 0; off >>= 1) {
    if (threadIdx.x < off) s[threadIdx.x] += s[threadIdx.x + off];
    __syncthreads();
  }
  if (threadIdx.x == 0) bsum[blockIdx.x] = s[0];
}

__global__ __launch_bounds__(256) void scan_small(int* __restrict__ bsum, int nb) {
  __shared__ int s[256];
  __shared__ int carry_s;
  if (threadIdx.x == 0) carry_s = 0;
  __syncthreads();
  for (int base = 0; base < nb; base += 256) {
    int idx = base + threadIdx.x;
    int v = (idx < nb) ? bsum[idx] : 0;
    s[threadIdx.x] = v;
    __syncthreads();
    for (int off = 1; off < 256; off <<= 1) {
      int t = (threadIdx.x >= (unsigned)off) ? s[threadIdx.x - off] : 0;
      __syncthreads();
      s[threadIdx.x] += t;
      __syncthreads();
    }
    int carry = carry_s;
    if (idx < nb) bsum[idx] = carry + s[threadIdx.x] - v;  // exclusive
    __syncthreads();
    if (threadIdx.x == 255) carry_s = carry + s[255];
    __syncthreads();
  }
}

__global__ __launch_bounds__(256) void scan_final(const u64* __restrict__ packed,
                                                  const int* __restrict__ boff,
                                                  int* __restrict__ rowptr,
                                                  float* __restrict__ dinv,
                                                  int n, int e_total) {
  __shared__ int s[256];
  int i = blockIdx.x * 256 + threadIdx.x;
  u64 p = (i < n) ? packed[i] : 0ull;
  int v = (int)(p >> 48);
  s[threadIdx.x] = v;
  __syncthreads();
  for (int off = 1; off < 256; off <<= 1) {
    int t = (threadIdx.x >= (unsigned)off) ? s[threadIdx.x - off] : 0;
    __syncthreads();
    s[threadIdx.x] += t;
    __syncthreads();
  }
  if (i < n) {
    rowptr[i] = boff[blockIdx.x] + s[threadIdx.x] - v;
    float deg = 1.0f + (float)(p & DEG_MASK) * (1.0f / WSCALE);
    dinv[i] = rsqrtf(deg);
  }
  if (i == 0) rowptr[n] = e_total;
}

// NO atomics: slot = rowptr[col] + rank.
__global__ __launch_bounds__(256) void edge_fill(const int* __restrict__ ei32,
                                                 const float* __restrict__ w,
                                                 const float* __restrict__ dinv,
                                                 const int* __restrict__ rowptr,
                                                 const unsigned short* __restrict__ rank,
                                                 int2* __restrict__ csr,
                                                 const int* __restrict__ flag, int e) {
  int i = blockIdx.x * 256 + threadIdx.x;
  if (i >= e) return;
  int is64 = *flag;
  int r, c;
  if (is64) { r = ei32[2 * i]; c = ei32[2 * (e + i)]; }
  else      { r = ei32[i];     c = ei32[e + i]; }
  float nrm = dinv[r] * w[i] * dinv[c];
  int pos = rowptr[c] + (int)rank[i];
  csr[pos] = make_int2(r, __float_as_int(nrm));
}

// out = f(A...)[N,128] @ W[128,OC] (+ bias). OC = 32*CPT.
// MODE 0: A = A0; MODE 1: A = relu(bn0(A0)); MODE 2: A = relu(bn1(A1)+
// relu(bn0(A0))) with fp32 side-store of A (h2, in-place over A0 is safe);
// MODE 3: A = relu(bn1(A1)+A0).
// BF16O: write ONLY bf16 out (outh); else fp32 out.
template <int CPT, int MODE, bool BF16O>
__global__ __launch_bounds__(256) void gemm_k128f(const float* A0, const float* A1,
                                                  const float* __restrict__ scsh0,
                                                  const float* __restrict__ scsh1,
                                                  float* side,
                                                  const float* __restrict__ W,
                                                  const float* __restrict__ bias,
                                                  float* __restrict__ out,
                                                  unsigned* __restrict__ outh, int n) {
  constexpr int OC = 32 * CPT;
  __shared__ float As[64][128];
  const int tid = threadIdx.x;
  const int r0 = blockIdx.x * 64;
  const int c4s = (tid & 31) << 2;   // feature quad, constant per thread
  float4 sc0, sh0, sc1, sh1;
  if (MODE == 1 || MODE == 2) {
    sc0 = *reinterpret_cast<const float4*>(&scsh0[c4s]);
    sh0 = *reinterpret_cast<const float4*>(&scsh0[128 + c4s]);
  }
  if (MODE == 2 || MODE == 3) {
    sc1 = *reinterpret_cast<const float4*>(&scsh1[c4s]);
    sh1 = *reinterpret_cast<const float4*>(&scsh1[128 + c4s]);
  }
  #pragma unroll
  for (int i = 0; i < 8; ++i) {
    int idx = tid + i * 256;
    int row = idx >> 5;
    int gr = r0 + row;
    float4 v = make_float4(0.f, 0.f, 0.f, 0.f);
    if (gr < n) {
      size_t base = (size_t)gr * 128 + c4s;
      if (MODE == 0) {
        v = *reinterpret_cast<const float4*>(&A0[base]);
      } else if (MODE == 1) {
        float4 a = *reinterpret_cast<const float4*>(&A0[base]);
        v.x = fmaxf(fmaf(a.x, sc0.x, sh0.x), 0.f);
        v.y = fmaxf(fmaf(a.y, sc0.y, sh0.y), 0.f);
        v.z = fmaxf(fmaf(a.z, sc0.z, sh0.z), 0.f);
        v.w = fmaxf(fmaf(a.w, sc0.w, sh0.w), 0.f);
      } else if (MODE == 2) {
        float4 a = *reinterpret_cast<const float4*>(&A0[base]);
        float4 b = *reinterpret_cast<const float4*>(&A1[base]);
        float hx = fmaxf(fmaf(a.x, sc0.x, sh0.x), 0.f);
        float hy = fmaxf(fmaf(a.y, sc0.y, sh0.y), 0.f);
        float hz = fmaxf(fmaf(a.z, sc0.z, sh0.z), 0.f);
        float hw = fmaxf(fmaf(a.w, sc0.w, sh0.w), 0.f);
        v.x = fmaxf(fmaf(b.x, sc1.x, sh1.x) + hx, 0.f);
        v.y = fmaxf(fmaf(b.y, sc1.y, sh1.y) + hy, 0.f);
        v.z = fmaxf(fmaf(b.z, sc1.z, sh1.z) + hz, 0.f);
        v.w = fmaxf(fmaf(b.w, sc1.w, sh1.w) + hw, 0.f);
        *reinterpret_cast<float4*>(&side[base]) = v;   // h2 in-place (fp32)
      } else {  // MODE 3
        float4 a = *reinterpret_cast<const float4*>(&A0[base]);
        float4 b = *reinterpret_cast<const float4*>(&A1[base]);
        v.x = fmaxf(fmaf(b.x, sc1.x, sh1.x) + a.x, 0.f);
        v.y = fmaxf(fmaf(b.y, sc1.y, sh1.y) + a.y, 0.f);
        v.z = fmaxf(fmaf(b.z, sc1.z, sh1.z) + a.z, 0.f);
        v.w = fmaxf(fmaf(b.w, sc1.w, sh1.w) + a.w, 0.f);
      }
    }
    *reinterpret_cast<float4*>(&As[row][c4s]) = v;
  }
  __syncthreads();

  const int lc = (tid & 31) * CPT;
  const int lr = (tid >> 5) * 8;
  float acc[8][CPT];
  #pragma unroll
  for (int i = 0; i < 8; ++i)
    #pragma unroll
    for (int j = 0; j < CPT; ++j) acc[i][j] = 0.f;

  #pragma unroll 2
  for (int k4 = 0; k4 < 128; k4 += 4) {
    float a[8][4];
    #pragma unroll
    for (int i = 0; i < 8; ++i) {
      float4 t = *reinterpret_cast<const float4*>(&As[lr + i][k4]);
      a[i][0] = t.x; a[i][1] = t.y; a[i][2] = t.z; a[i][3] = t.w;
    }
    #pragma unroll
    for (int kk = 0; kk < 4; ++kk) {
      float wv[CPT];
      const float* wrow = &W[(size_t)(k4 + kk) * OC + lc];
      if constexpr (CPT == 4) {
        float4 t = *reinterpret_cast<const float4*>(wrow);
        wv[0] = t.x; wv[1] = t.y; wv[2] = t.z; wv[3] = t.w;
      } else {
        float2 t = *reinterpret_cast<const float2*>(wrow);
        wv[0] = t.x; wv[1] = t.y;
      }
      #pragma unroll
      for (int i = 0; i < 8; ++i)
        #pragma unroll
        for (int j = 0; j < CPT; ++j)
          acc[i][j] = fmaf(a[i][kk], wv[j], acc[i][j]);
    }
  }

  float bv[CPT];
  #pragma unroll
  for (int j = 0; j < CPT; ++j) bv[j] = bias ? bias[lc + j] : 0.f;
  #pragma unroll
  for (int i = 0; i < 8; ++i) {
    int gr = r0 + lr + i;
    if (gr < n) {
      if constexpr (BF16O) {
        // bf16 row-major [N][OC]; this thread's CPT cols -> CPT/2 uints
        unsigned pk0 = bf16pack2(acc[i][0] + bv[0], acc[i][1] + bv[1]);
        if constexpr (CPT == 4) {
          unsigned pk1 = bf16pack2(acc[i][2] + bv[2], acc[i][3] + bv[3]);
          *reinterpret_cast<uint2*>(&outh[(size_t)gr * (OC / 2) + (lc >> 1)]) =
              make_uint2(pk0, pk1);
        } else {
          outh[(size_t)gr * (OC / 2) + (lc >> 1)] = pk0;
        }
      } else {
        if constexpr (CPT == 4) {
          float4 o = make_float4(acc[i][0] + bv[0], acc[i][1] + bv[1],
                                 acc[i][2] + bv[2], acc[i][3] + bv[3]);
          *reinterpret_cast<float4*>(&out[(size_t)gr * OC + lc]) = o;
        } else {
          float2 o = make_float2(acc[i][0] + bv[0], acc[i][1] + bv[1]);
          *reinterpret_cast<float2*>(&out[(size_t)gr * OC + lc]) = o;
        }
      }
    }
  }
}

// wave-per-node CSR gather over BF16 rows (256B/row): one node per wave,
// 4 independent row loads in flight; fp32 accumulate; fp32 output.
__global__ __launch_bounds__(256) void gcn_gather(const unsigned* __restrict__ h,
                                                  const int* __restrict__ rowptr,
                                                  const int2* __restrict__ csr,
                                                  const float* __restrict__ dinv,
                                                  const float* __restrict__ bias,
                                                  float* __restrict__ out, int n) {
  int wave = threadIdx.x >> 6;
  int lane = threadIdx.x & 63;
  int node = blockIdx.x * 4 + wave;
  if (node >= n) return;
  float di = dinv[node];
  unsigned hv = h[(size_t)node * 64 + lane];
  float s = di * di;
  float ax = s * __uint_as_float(hv << 16);
  float ay = s * __uint_as_float(hv & 0xFFFF0000u);
  int e0 = rowptr[node], e1 = rowptr[node + 1];
  int e = e0;
  for (; e + 3 < e1; e += 4) {
    int2 pa = csr[e];
    int2 pb = csr[e + 1];
    int2 pc = csr[e + 2];
    int2 pd = csr[e + 3];
    unsigned sa = h[(size_t)pa.x * 64 + lane];
    unsigned sb = h[(size_t)pb.x * 64 + lane];
    unsigned sc = h[(size_t)pc.x * 64 + lane];
    unsigned sd = h[(size_t)pd.x * 64 + lane];
    float na = __int_as_float(pa.y), nb = __int_as_float(pb.y);
    float nc = __int_as_float(pc.y), nd = __int_as_float(pd.y);
    ax = fmaf(na, __uint_as_float(sa << 16), ax);
    ay = fmaf(na, __uint_as_float(sa & 0xFFFF0000u), ay);
    ax = fmaf(nb, __uint_as_float(sb << 16), ax);
    ay = fmaf(nb, __uint_as_float(sb & 0xFFFF0000u), ay);
    ax = fmaf(nc, __uint_as_float(sc << 16), ax);
    ay = fmaf(nc, __uint_as_float(sc & 0xFFFF0000u), ay);
    ax = fmaf(nd, __uint_as_float(sd << 16), ax);
    ay = fmaf(nd, __uint_as_float(sd & 0xFFFF0000u), ay);
  }
  for (; e < e1; ++e) {
    int2 p = csr[e];
    unsigned sv = h[(size_t)p.x * 64 + lane];
    float nm = __int_as_float(p.y);
    ax = fmaf(nm, __uint_as_float(sv << 16), ax);
    ay = fmaf(nm, __uint_as_float(sv & 0xFFFF0000u), ay);
  }
  int f = lane * 2;
  float2 o = make_float2(ax + bias[f], ay + bias[f + 1]);
  reinterpret_cast<float2*>(out)[(size_t)node * 64 + lane] = o;
}

__global__ __launch_bounds__(256) void bn_stats(const float* __restrict__ h,
                                                float* __restrict__ stats, int n) {
  int f = threadIdx.x & 127;
  int half = threadIdx.x >> 7;
  float s = 0.f, q = 0.f;
  for (int r = blockIdx.x * 2 + half; r < n; r += gridDim.x * 2) {
    float v = h[(size_t)r * 128 + f];
    s += v;
    q = fmaf(v, v, q);
  }
  __shared__ float ls[256], lq[256];
  ls[threadIdx.x] = s; lq[threadIdx.x] = q;
  __syncthreads();
  if (half == 0) {
    s += ls[threadIdx.x + 128];
    q += lq[threadIdx.x + 128];
    atomicAdd(&stats[f], s);
    atomicAdd(&stats[128 + f], q);
  }
}

__global__ void bn_finalize(const float* __restrict__ stats,
                            const float* __restrict__ g,
                            const float* __restrict__ be,
                            float* __restrict__ scsh, float inv_n) {
  int f = threadIdx.x;  // 128 threads
  float mean = stats[f] * inv_n;
  float var = stats[128 + f] * inv_n - mean * mean;
  float sc = g[f] * rsqrtf(var + 1e-5f);
  scsh[f] = sc;
  scsh[128 + f] = be[f] - mean * sc;
}

extern "C" void kernel_launch(void* const* d_in, const int* in_sizes, int n_in,
                              void* d_out, int out_size, void* d_ws, size_t ws_size,
                              hipStream_t stream) {
  const float* x   = (const float*)d_in[0];
  const int*   ei  = (const int*)d_in[1];      // int32 on device (probed for int64)
  const float* ew  = (const float*)d_in[2];
  const float* W1  = (const float*)d_in[3];
  const float* b1  = (const float*)d_in[4];
  const float* g1  = (const float*)d_in[5];
  const float* be1 = (const float*)d_in[6];
  const float* W2  = (const float*)d_in[7];
  const float* b2  = (const float*)d_in[8];
  const float* g2  = (const float*)d_in[9];
  const float* be2 = (const float*)d_in[10];
  const float* W3  = (const float*)d_in[11];
  const float* b3  = (const float*)d_in[12];
  const float* g3  = (const float*)d_in[13];
  const float* be3 = (const float*)d_in[14];
  const float* Wh  = (const float*)d_in[15];
  const float* bh  = (const float*)d_in[16];

  const int N = in_sizes[0] / 128;
  const int E = in_sizes[2];

  char* base = (char*)d_ws;
  size_t off = 0;
  auto alloc = [&](size_t bytes) -> void* {
    off = (off + 511) & ~size_t(511);
    void* p = base + off;
    off += bytes;
    return p;
  };
  int*            flag    = (int*)alloc(4);
  u64*            packed  = (u64*)alloc((size_t)N * 8);
  float*          dinv    = (float*)alloc((size_t)N * 4);
  int*            rowptr  = (int*)alloc((size_t)(N + 1) * 4);
  int*            bsum    = (int*)alloc(1024 * 4);
  float*          stats   = (float*)alloc(768 * 4);
  float*          scshAll = (float*)alloc(768 * 4);
  unsigned short* rank    = (unsigned short*)alloc((size_t)E * 2);
  int2*           csr     = (int2*)alloc((size_t)E * 8);
  unsigned*       Ph      = (unsigned*)alloc((size_t)N * 128 * 2);  // bf16 P
  float*          Q       = (float*)alloc((size_t)N * 128 * 4);     // C1 -> h2
  float*          R       = (float*)alloc((size_t)N * 128 * 4);     // C2 -> C3
  (void)ws_size; (void)n_in; (void)out_size;

  const int nb = (N + 255) / 256;
  const int eb = (E + 255) / 256;
  const int gb = (N + 63) / 64;
  const int cb = (N + 3) / 4;   // one node per wave (R8/R12-validated schedule)

  // ---- graph normalization + CSR build ----
  detect_i64<<<1, 64, 0, stream>>>(ei, flag);
  init_k<<<nb, 256, 0, stream>>>(packed, stats, N);
  edge_hist<<<eb, 256, 0, stream>>>(ei, ew, packed, rank, flag, E);
  scan_blocksum<<<nb, 256, 0, stream>>>(packed, bsum, N);
  scan_small<<<1, 256, 0, stream>>>(bsum, nb);
  scan_final<<<nb, 256, 0, stream>>>(packed, bsum, rowptr, dinv, N, E);
  edge_fill<<<eb, 256, 0, stream>>>(ei, ew, dinv, rowptr, rank, csr, flag, E);

  // ---- layer 1: Ph = bf16(x@W1); Q = C1 = agg(Ph); stats0
  gemm_k128f<4, 0, true><<<gb, 256, 0, stream>>>(x, nullptr, nullptr, nullptr,
                                                 nullptr, W1, nullptr, nullptr, Ph, N);
  gcn_gather<<<cb, 256, 0, stream>>>(Ph, rowptr, csr, dinv, b1, Q, N);
  bn_stats<<<512, 256, 0, stream>>>(Q, stats + 0, N);
  bn_finalize<<<1, 128, 0, stream>>>(stats + 0, g1, be1, scshAll + 0, 1.0f / N);

  // ---- layer 2: Ph = bf16(relu(bn1(C1))@W2); R = C2 = agg(Ph); stats1
  gemm_k128f<4, 1, true><<<gb, 256, 0, stream>>>(Q, nullptr, scshAll + 0, nullptr,
                                                 nullptr, W2, nullptr, nullptr, Ph, N);
  gcn_gather<<<cb, 256, 0, stream>>>(Ph, rowptr, csr, dinv, b2, R, N);
  bn_stats<<<512, 256, 0, stream>>>(R, stats + 256, N);
  bn_finalize<<<1, 128, 0, stream>>>(stats + 256, g2, be2, scshAll + 256, 1.0f / N);

  // ---- layer 3: h2 = relu(bn2(C2)+relu(bn1(C1))) side-stored fp32 over Q;
  //               Ph = bf16(h2@W3); R = C3 = agg(Ph); stats2
  gemm_k128f<4, 2, true><<<gb, 256, 0, stream>>>(Q, R, scshAll + 0, scshAll + 256,
                                                 Q, W3, nullptr, nullptr, Ph, N);
  gcn_gather<<<cb, 256, 0, stream>>>(Ph, rowptr, csr, dinv, b3, R, N);
  bn_stats<<<512, 256, 0, stream>>>(R, stats + 512, N);
  bn_finalize<<<1, 128, 0, stream>>>(stats + 512, g3, be3, scshAll + 512, 1.0f / N);

  // ---- head: d_out = relu(bn3(C3)+h2) @ Wh + bh  (pure fp32)
  gemm_k128f<2, 3, false><<<gb, 256, 0, stream>>>(Q, R, nullptr, scshAll + 512,
                                                  nullptr, Wh, bh, (float*)d_out,
                                                  nullptr, N);
}